// Round 4
// baseline (2640.016 us; speedup 1.0000x reference)
//
#include <hip/hip_runtime.h>
#include <stdint.h>

#define BATCH 8192
#define ADIM 128
#define HDIM 256
#define VDIM 64
#define NSTEP 20
#define TB 8     // samples per block: 1024 blocks -> 4 blocks/CU (was 2)
#define TBP 10   // padded inner dim: 8B (float2) alignment, breaks write conflicts

typedef union { float4 v; float f[4]; } F4;
typedef union { float2 v; float f[2]; } F2;

// ---------------- Threefry-2x32 (exactly JAX's lowering) ----------------
__device__ __forceinline__ uint32_t rotl32(uint32_t x, uint32_t d) {
  return (x << d) | (x >> (32u - d));
}
__device__ __forceinline__ void tf4(uint32_t& x0, uint32_t& x1, int r0, int r1, int r2, int r3) {
  x0 += x1; x1 = rotl32(x1, r0); x1 ^= x0;
  x0 += x1; x1 = rotl32(x1, r1); x1 ^= x0;
  x0 += x1; x1 = rotl32(x1, r2); x1 ^= x0;
  x0 += x1; x1 = rotl32(x1, r3); x1 ^= x0;
}
__device__ __forceinline__ void threefry2x32(uint32_t k0, uint32_t k1, uint32_t x0, uint32_t x1,
                                             uint32_t& o0, uint32_t& o1) {
  uint32_t k2 = k0 ^ k1 ^ 0x1BD11BDAu;
  x0 += k0; x1 += k1;
  tf4(x0, x1, 13, 15, 26, 6);  x0 += k1; x1 += k2 + 1u;
  tf4(x0, x1, 17, 29, 16, 24); x0 += k2; x1 += k0 + 2u;
  tf4(x0, x1, 13, 15, 26, 6);  x0 += k0; x1 += k1 + 3u;
  tf4(x0, x1, 17, 29, 16, 24); x0 += k1; x1 += k2 + 4u;
  tf4(x0, x1, 13, 15, 26, 6);  x0 += k2; x1 += k0 + 5u;
  o0 = x0; o1 = x1;
}

__device__ __forceinline__ float sigm(float x) { return 1.0f / (1.0f + expf(-x)); }

// ---------------- prep: transpose weights into workspace ----------------
// ws layout (floats): WhhT[256][1024] @0, WvT[256][64] @262144,
//                     WaT[128][256] @278528, WihT[64][1024] @311296
__global__ void prep_kernel(const float* __restrict__ Whh, const float* __restrict__ Wv,
                            const float* __restrict__ Wa, const float* __restrict__ Wih,
                            float* __restrict__ ws) {
  int n = blockIdx.x * blockDim.x + threadIdx.x;
  int stride = gridDim.x * blockDim.x;
  float* WhhT = ws;
  float* WvT  = ws + 262144;
  float* WaT  = ws + 278528;
  float* WihT = ws + 311296;
  for (int i = n; i < 256 * 1024; i += stride) { int k = i >> 10, r = i & 1023; WhhT[i] = Whh[r * 256 + k]; }
  for (int i = n; i < 256 * 64;   i += stride) { int k = i >> 6,  v = i & 63;   WvT[i]  = Wv[v * 256 + k]; }
  for (int i = n; i < 128 * 256;  i += stride) { int k = i >> 8,  u = i & 255;  WaT[i]  = Wa[u * 128 + k]; }
  for (int i = n; i < 64 * 1024;  i += stride) { int v = i >> 10, r = i & 1023; WihT[i] = Wih[r * 64 + v]; }
}

// ---------------- main persistent kernel ----------------
// 1024 blocks x 256 threads; block owns TB=8 samples for all 21 steps.
// Disjoint tiling of 256 units x 8 samples: wave w owns units [64w,64w+64);
// lane: uu=lane&15 -> units 64w+4uu..+3, sq=lane>>4 -> samples 2sq..+1.
// 4 blocks/CU (16 waves/CU) for L2-latency hiding; weight reads stay
// 4-lane-same-address coalesced. All private arrays statically indexed.
__global__ __launch_bounds__(256, 4) void sender_main(
    const float* __restrict__ attr, const float* __restrict__ b_a,
    const float* __restrict__ b_ih, const float* __restrict__ b_hh,
    const float* __restrict__ b_v,
    const float* __restrict__ WhhT, const float* __restrict__ WvT,
    const float* __restrict__ WaT, const float* __restrict__ WihT,
    float* __restrict__ out) {
  __shared__ float h_s[HDIM][TBP];
  __shared__ float attr_s[ADIM][TBP];
  __shared__ float slp_s[TB], plp_s[TB], ep_s[TB];
  __shared__ int ch_s[TB];

  const int tid = threadIdx.x;
  const int w = tid >> 6;        // wave id: owns units [64w,64w+64); samples 2w..+1 for sampling
  const int lane = tid & 63;
  const int uu = lane & 15;      // unit subgroup
  const int sq = lane >> 4;      // sample pair index
  const int u4 = (w << 6) + (uu << 2);  // first of this thread's 4 units
  const int s2 = sq << 1;               // first of this thread's 2 samples
  const int w2 = w << 1;                // first sample this wave samples
  const int b0 = blockIdx.x * TB;

  if (tid < TB) { slp_s[tid] = 0.0f; plp_s[tid] = 0.0f; ep_s[tid] = 1.0f; }

  // ---- stage attr tile, transposed to k-major ----
  {
    int r = tid >> 5;            // 0..7
    int cm = (tid & 31) << 2;    // 0,4,...,124
    F4 vv; vv.v = *(const float4*)&attr[(size_t)(b0 + r) * ADIM + cm];
    attr_s[cm + 0][r] = vv.f[0];
    attr_s[cm + 1][r] = vv.f[1];
    attr_s[cm + 2][r] = vv.f[2];
    attr_s[cm + 3][r] = vv.f[3];
  }
  __syncthreads();

  // ---- h0 = attr @ W_a^T + b_a ----
  {
    float acc[2][4];  // [sample][unit]
    #pragma unroll
    for (int s = 0; s < 2; ++s)
      #pragma unroll
      for (int j = 0; j < 4; ++j) acc[s][j] = 0.0f;
    for (int k = 0; k < ADIM; ++k) {
      F2 av; av.v = *(const float2*)&attr_s[k][s2];
      F4 wv; wv.v = *(const float4*)&WaT[(k << 8) + u4];
      #pragma unroll
      for (int s = 0; s < 2; ++s)
        #pragma unroll
        for (int j = 0; j < 4; ++j) acc[s][j] = fmaf(av.f[s], wv.f[j], acc[s][j]);
    }
    F4 ba; ba.v = *(const float4*)&b_a[u4];
    #pragma unroll
    for (int j = 0; j < 4; ++j) {
      F2 hv2;
      #pragma unroll
      for (int s = 0; s < 2; ++s) hv2.f[s] = acc[s][j] + ba.f[j];
      *(float2*)&h_s[u4 + j][s2] = hv2.v;
    }
  }
  __syncthreads();

  // persistent per-thread state: cell state for [sample][unit]
  float c_r[2][4];
  #pragma unroll
  for (int s = 0; s < 2; ++s)
    #pragma unroll
    for (int j = 0; j < 4; ++j) c_r[s][j] = 0.0f;

  F4 bg[4];  // b_ih + b_hh per gate, for this thread's 4 units
  #pragma unroll
  for (int g = 0; g < 4; ++g) {
    F4 bi; bi.v = *(const float4*)&b_ih[(g << 8) + u4];
    F4 bh; bh.v = *(const float4*)&b_hh[(g << 8) + u4];
    #pragma unroll
    for (int j = 0; j < 4; ++j) bg[g].f[j] = bi.f[j] + bh.f[j];
  }
  const float bv = b_v[lane];

  // ---- initial LSTM step, x = 0 ----
  {
    float ga[2][4][4];  // [sample][gate][unit]
    #pragma unroll
    for (int s = 0; s < 2; ++s)
      #pragma unroll
      for (int g = 0; g < 4; ++g)
        #pragma unroll
        for (int j = 0; j < 4; ++j) ga[s][g][j] = 0.0f;
    #pragma unroll 2
    for (int k = 0; k < HDIM; ++k) {
      F2 hv; hv.v = *(const float2*)&h_s[k][s2];
      const float* wr = WhhT + (k << 10) + u4;
      F4 w0, w1, w2r, w3;
      w0.v  = *(const float4*)(wr);
      w1.v  = *(const float4*)(wr + 256);
      w2r.v = *(const float4*)(wr + 512);
      w3.v  = *(const float4*)(wr + 768);
      #pragma unroll
      for (int s = 0; s < 2; ++s) {
        float hd = hv.f[s];
        #pragma unroll
        for (int j = 0; j < 4; ++j) {
          ga[s][0][j] = fmaf(hd, w0.f[j],  ga[s][0][j]);
          ga[s][1][j] = fmaf(hd, w1.f[j],  ga[s][1][j]);
          ga[s][2][j] = fmaf(hd, w2r.f[j], ga[s][2][j]);
          ga[s][3][j] = fmaf(hd, w3.f[j],  ga[s][3][j]);
        }
      }
    }
    __syncthreads();  // all reads of h_s done before overwrite
    float hn_r[2][4];  // [sample][unit]
    #pragma unroll
    for (int s = 0; s < 2; ++s)
      #pragma unroll
      for (int j = 0; j < 4; ++j) {
        float gi = ga[s][0][j] + bg[0].f[j];
        float gf = ga[s][1][j] + bg[1].f[j];
        float gg = ga[s][2][j] + bg[2].f[j];
        float go = ga[s][3][j] + bg[3].f[j];
        float cn = sigm(gf) * c_r[s][j] + sigm(gi) * tanhf(gg);
        float hn = sigm(go) * tanhf(cn);
        c_r[s][j] = cn;
        hn_r[s][j] = hn;
      }
    #pragma unroll
    for (int j = 0; j < 4; ++j) {
      F2 hv2;
      #pragma unroll
      for (int s = 0; s < 2; ++s) hv2.f[s] = hn_r[s][j];
      *(float2*)&h_s[u4 + j][s2] = hv2.v;
    }
    __syncthreads();
  }

  // ---- 20 sampled steps ----
  for (int l = 0; l < NSTEP; ++l) {
    // step key: foldlike split of key(42)
    uint32_t kl0, kl1;
    threefry2x32(0u, 42u, 0u, (uint32_t)l, kl0, kl1);

    const bool last = (l == NSTEP - 1);
    float la[2] = {0.0f, 0.0f};  // logits for samples 2w..+1, v=lane
    float ga[2][4][4];  // [sample][gate][unit]
    #pragma unroll
    for (int s = 0; s < 2; ++s)
      #pragma unroll
      for (int g = 0; g < 4; ++g)
        #pragma unroll
        for (int j = 0; j < 4; ++j) ga[s][g][j] = 0.0f;

    if (!last) {
      #pragma unroll 2
      for (int k = 0; k < HDIM; ++k) {
        F2 hv; hv.v = *(const float2*)&h_s[k][s2];   // h for gate samples
        F2 hl; hl.v = *(const float2*)&h_s[k][w2];   // h for this wave's logit samples
        float wv = WvT[(k << 6) | lane];
        const float* wr = WhhT + (k << 10) + u4;
        F4 w0, w1, w2r, w3;
        w0.v  = *(const float4*)(wr);
        w1.v  = *(const float4*)(wr + 256);
        w2r.v = *(const float4*)(wr + 512);
        w3.v  = *(const float4*)(wr + 768);
        #pragma unroll
        for (int s = 0; s < 2; ++s) {
          la[s] = fmaf(hl.f[s], wv, la[s]);
          float hd = hv.f[s];
          #pragma unroll
          for (int j = 0; j < 4; ++j) {
            ga[s][0][j] = fmaf(hd, w0.f[j],  ga[s][0][j]);
            ga[s][1][j] = fmaf(hd, w1.f[j],  ga[s][1][j]);
            ga[s][2][j] = fmaf(hd, w2r.f[j], ga[s][2][j]);
            ga[s][3][j] = fmaf(hd, w3.f[j],  ga[s][3][j]);
          }
        }
      }
    } else {
      #pragma unroll 2
      for (int k = 0; k < HDIM; ++k) {
        F2 hl; hl.v = *(const float2*)&h_s[k][w2];
        float wv = WvT[(k << 6) | lane];
        #pragma unroll
        for (int s = 0; s < 2; ++s) la[s] = fmaf(hl.f[s], wv, la[s]);
      }
    }

    // ---- sampling: wave w handles samples 2w..+1; lane holds logit[b][lane] ----
    #pragma unroll
    for (int db = 0; db < 2; ++db) {
      float x = la[db] + bv;  // logits = h@W_v^T + b_v
      // wave max
      float m = x;
      #pragma unroll
      for (int o = 32; o > 0; o >>= 1) m = fmaxf(m, __shfl_xor(m, o));
      float e = expf(x - m);
      float s = e;
      #pragma unroll
      for (int o = 32; o > 0; o >>= 1) s += __shfl_xor(s, o);
      float lse = logf(s);
      float logp = x - m - lse;
      float p = expf(logp);
      float pe = p * logp;
      #pragma unroll
      for (int o = 32; o > 0; o >>= 1) pe += __shfl_xor(pe, o);
      // gumbel noise via threefry (partitionable random_bits path)
      uint32_t idx = ((uint32_t)(b0 + w2 + db) << 6) | (uint32_t)lane;
      uint32_t r0, r1;
      threefry2x32(kl0, kl1, 0u, idx, r0, r1);
      uint32_t bits = r0 ^ r1;
      float f01 = __uint_as_float((bits >> 9) | 0x3f800000u) - 1.0f;
      const float TINY = 1.17549435e-38f;
      float u = fmaxf(TINY, f01 + TINY);
      float gn = -logf(-logf(u));
      float y = gn + x;
      // argmax, first index wins ties
      float by = y; int bi = lane;
      #pragma unroll
      for (int o = 32; o > 0; o >>= 1) {
        float oy = __shfl_xor(by, o);
        int oi = __shfl_xor(bi, o);
        if (oy > by || (oy == by && oi < bi)) { by = oy; bi = oi; }
      }
      float lp = __shfl(logp, bi, 64);
      if (lane == 0) {
        int bb = w2 + db;
        ch_s[bb] = bi;
        slp_s[bb] += lp;
        plp_s[bb] += pe;
        ep_s[bb] *= expf(lp);
        out[(size_t)(b0 + bb) * NSTEP + l] = (float)bi;
      }
    }

    if (!last) {
      __syncthreads();  // everyone finished reading h_s; ch_s visible
      float hn_r[2][4];  // [sample][unit]
      #pragma unroll
      for (int s = 0; s < 2; ++s) {
        const float* wi = WihT + (ch_s[s2 + s] << 10) + u4;
        F4 wi0, wi1, wi2, wi3;
        wi0.v = *(const float4*)(wi);
        wi1.v = *(const float4*)(wi + 256);
        wi2.v = *(const float4*)(wi + 512);
        wi3.v = *(const float4*)(wi + 768);
        #pragma unroll
        for (int j = 0; j < 4; ++j) {
          float gi = ga[s][0][j] + wi0.f[j] + bg[0].f[j];
          float gf = ga[s][1][j] + wi1.f[j] + bg[1].f[j];
          float gg = ga[s][2][j] + wi2.f[j] + bg[2].f[j];
          float go = ga[s][3][j] + wi3.f[j] + bg[3].f[j];
          float cn = sigm(gf) * c_r[s][j] + sigm(gi) * tanhf(gg);
          float hn = sigm(go) * tanhf(cn);
          c_r[s][j] = cn;
          hn_r[s][j] = hn;
        }
      }
      #pragma unroll
      for (int j = 0; j < 4; ++j) {
        F2 hv2;
        #pragma unroll
        for (int s = 0; s < 2; ++s) hv2.f[s] = hn_r[s][j];
        *(float2*)&h_s[u4 + j][s2] = hv2.v;
      }
      __syncthreads();
    }
  }

  __syncthreads();
  if (tid < TB) {
    int bb = b0 + tid;
    out[(size_t)BATCH * NSTEP + bb]             = slp_s[tid];
    out[(size_t)BATCH * NSTEP + BATCH + bb]     = plp_s[tid];
    out[(size_t)BATCH * NSTEP + 2 * BATCH + bb] = ep_s[tid];
  }
}

extern "C" void kernel_launch(void* const* d_in, const int* in_sizes, int n_in,
                              void* d_out, int out_size, void* d_ws, size_t ws_size,
                              hipStream_t stream) {
  // setup_inputs order:
  // 0 attrVector [8192,128], 1 W_a [256,128], 2 b_a [256], 3 W_ih [1024,64],
  // 4 W_hh [1024,256], 5 b_ih [1024], 6 b_hh [1024], 7 W_v [64,256], 8 b_v [64]
  const float* attr = (const float*)d_in[0];
  const float* W_a  = (const float*)d_in[1];
  const float* b_a  = (const float*)d_in[2];
  const float* W_ih = (const float*)d_in[3];
  const float* W_hh = (const float*)d_in[4];
  const float* b_ih = (const float*)d_in[5];
  const float* b_hh = (const float*)d_in[6];
  const float* W_v  = (const float*)d_in[7];
  const float* b_v  = (const float*)d_in[8];
  float* ws = (float*)d_ws;

  prep_kernel<<<256, 256, 0, stream>>>(W_hh, W_v, W_a, W_ih, ws);
  sender_main<<<BATCH / TB, 256, 0, stream>>>(
      attr, b_a, b_ih, b_hh, b_v,
      ws, ws + 262144, ws + 278528, ws + 311296,
      (float*)d_out);
}

// Round 5
// 1525.374 us; speedup vs baseline: 1.7307x; 1.7307x over previous
//
#include <hip/hip_runtime.h>
#include <stdint.h>

#define BATCH 8192
#define ADIM 128
#define HDIM 256
#define VDIM 64
#define NSTEP 20
#define TB 16
#define HSP 20   // h_s row pad in floats: 80B rows stay 16B-aligned, break pow2 conflicts

typedef union { float4 v; float f[4]; } F4;

// ---------------- Threefry-2x32 (exactly JAX's lowering) ----------------
__device__ __forceinline__ uint32_t rotl32(uint32_t x, uint32_t d) {
  return (x << d) | (x >> (32u - d));
}
__device__ __forceinline__ void tf4(uint32_t& x0, uint32_t& x1, int r0, int r1, int r2, int r3) {
  x0 += x1; x1 = rotl32(x1, r0); x1 ^= x0;
  x0 += x1; x1 = rotl32(x1, r1); x1 ^= x0;
  x0 += x1; x1 = rotl32(x1, r2); x1 ^= x0;
  x0 += x1; x1 = rotl32(x1, r3); x1 ^= x0;
}
__device__ __forceinline__ void threefry2x32(uint32_t k0, uint32_t k1, uint32_t x0, uint32_t x1,
                                             uint32_t& o0, uint32_t& o1) {
  uint32_t k2 = k0 ^ k1 ^ 0x1BD11BDAu;
  x0 += k0; x1 += k1;
  tf4(x0, x1, 13, 15, 26, 6);  x0 += k1; x1 += k2 + 1u;
  tf4(x0, x1, 17, 29, 16, 24); x0 += k2; x1 += k0 + 2u;
  tf4(x0, x1, 13, 15, 26, 6);  x0 += k0; x1 += k1 + 3u;
  tf4(x0, x1, 17, 29, 16, 24); x0 += k1; x1 += k2 + 4u;
  tf4(x0, x1, 13, 15, 26, 6);  x0 += k2; x1 += k0 + 5u;
  o0 = x0; o1 = x1;
}

__device__ __forceinline__ float sigm(float x) { return 1.0f / (1.0f + expf(-x)); }

// ---------------- prep: repack weights, gate-interleaved per unit ----------------
// ws layout (floats): WhhT4[256][256][4] @0      (k, unit, gate)  1 MB
//                     WvT  [256][64]     @262144 (k, v)
//                     WaT  [128][256]    @278528 (k, unit)
//                     WihT4[64][256][4]  @311296 (v, unit, gate)
__global__ void prep_kernel(const float* __restrict__ Whh, const float* __restrict__ Wv,
                            const float* __restrict__ Wa, const float* __restrict__ Wih,
                            float* __restrict__ ws) {
  int n = blockIdx.x * blockDim.x + threadIdx.x;
  int stride = gridDim.x * blockDim.x;
  float* WhhT4 = ws;
  float* WvT   = ws + 262144;
  float* WaT   = ws + 278528;
  float* WihT4 = ws + 311296;
  for (int i = n; i < 256 * 1024; i += stride) {
    int k = i >> 10, rem = i & 1023, u = rem >> 2, g = rem & 3;
    WhhT4[i] = Whh[((g << 8) + u) * 256 + k];
  }
  for (int i = n; i < 256 * 64; i += stride) { int k = i >> 6, v = i & 63; WvT[i] = Wv[v * 256 + k]; }
  for (int i = n; i < 128 * 256; i += stride) { int k = i >> 8, u = i & 255; WaT[i] = Wa[u * 128 + k]; }
  for (int i = n; i < 64 * 1024; i += stride) {
    int v = i >> 10, rem = i & 1023, u = rem >> 2, g = rem & 3;
    WihT4[i] = Wih[((g << 8) + u) * 64 + v];
  }
}

// ---------------- main persistent kernel ----------------
// 512 blocks x 256 threads; block owns TB=16 samples for all 21 steps.
// Lane = unit: thread owns unit u = 64w+lane, ALL 16 samples (4 gates each).
// Weight read per k = ONE lane-coalesced dwordx4 (16B/lane) -- 4x less
// TCP/L1 return traffic than the 4-lane-broadcast scheme (R3/R4 bottleneck:
// TCP charges per-lane bytes even for same-address reads).
// h lives in LDS as h_s[k][sample]; k-loop reads are all-lane-same-address
// broadcasts (conflict-free). Sampling mapping unchanged -> bit-exact.
__global__ __launch_bounds__(256, 2) void sender_main(
    const float* __restrict__ attr, const float* __restrict__ b_a,
    const float* __restrict__ b_ih, const float* __restrict__ b_hh,
    const float* __restrict__ b_v,
    const float* __restrict__ WhhT4, const float* __restrict__ WvT,
    const float* __restrict__ WaT, const float* __restrict__ WihT4,
    float* __restrict__ out) {
  __shared__ float h_s[HDIM][HSP];     // h_s[k][sample]
  __shared__ float attr_s[ADIM][HSP];  // attr_s[k][sample]
  __shared__ float slp_s[TB], plp_s[TB], ep_s[TB];
  __shared__ int ch_s[TB];

  const int tid = threadIdx.x;
  const int w = tid >> 6;         // wave id
  const int lane = tid & 63;
  const int u = (w << 6) + lane;  // unit owned by this thread
  const int w4 = w << 2;          // first sample this wave samples
  const int b0 = blockIdx.x * TB;

  if (tid < TB) { slp_s[tid] = 0.0f; plp_s[tid] = 0.0f; ep_s[tid] = 1.0f; }

  // ---- stage attr tile, transposed to k-major ----
  {
    int r = tid >> 5;            // 0..7
    int cm = (tid & 31) << 2;    // 0,4,...,124
    #pragma unroll
    for (int pass = 0; pass < 2; ++pass) {
      int row = r + (pass << 3);
      F4 vv; vv.v = *(const float4*)&attr[(size_t)(b0 + row) * ADIM + cm];
      attr_s[cm + 0][row] = vv.f[0];
      attr_s[cm + 1][row] = vv.f[1];
      attr_s[cm + 2][row] = vv.f[2];
      attr_s[cm + 3][row] = vv.f[3];
    }
  }
  __syncthreads();

  // ---- h0 = attr @ W_a^T + b_a : acc[s] for this thread's unit ----
  {
    float acc[16];
    #pragma unroll
    for (int s = 0; s < 16; ++s) acc[s] = 0.0f;
    #pragma unroll 2
    for (int k = 0; k < ADIM; ++k) {
      F4 a0, a1, a2, a3;
      a0.v = *(const float4*)&attr_s[k][0];
      a1.v = *(const float4*)&attr_s[k][4];
      a2.v = *(const float4*)&attr_s[k][8];
      a3.v = *(const float4*)&attr_s[k][12];
      float wa = WaT[(k << 8) + u];
      #pragma unroll
      for (int j = 0; j < 4; ++j) {
        acc[j]      = fmaf(a0.f[j], wa, acc[j]);
        acc[4 + j]  = fmaf(a1.f[j], wa, acc[4 + j]);
        acc[8 + j]  = fmaf(a2.f[j], wa, acc[8 + j]);
        acc[12 + j] = fmaf(a3.f[j], wa, acc[12 + j]);
      }
    }
    float ba = b_a[u];
    #pragma unroll
    for (int q = 0; q < 4; ++q) {
      F4 hv4;
      #pragma unroll
      for (int j = 0; j < 4; ++j) hv4.f[j] = acc[q * 4 + j] + ba;
      *(float4*)&h_s[u][q * 4] = hv4.v;
    }
  }
  __syncthreads();

  // persistent per-thread state: cell state for 16 samples (this unit)
  float c_r[16];
  #pragma unroll
  for (int s = 0; s < 16; ++s) c_r[s] = 0.0f;

  float bg[4];  // b_ih + b_hh per gate for this unit
  #pragma unroll
  for (int g = 0; g < 4; ++g) bg[g] = b_ih[(g << 8) + u] + b_hh[(g << 8) + u];
  const float bv = b_v[lane];

  // ---- initial LSTM step, x = 0 ----
  {
    float ga[16][4];  // [sample][gate]
    #pragma unroll
    for (int s = 0; s < 16; ++s)
      #pragma unroll
      for (int g = 0; g < 4; ++g) ga[s][g] = 0.0f;
    #pragma unroll 2
    for (int k = 0; k < HDIM; ++k) {
      F4 h0q, h1q, h2q, h3q;
      h0q.v = *(const float4*)&h_s[k][0];
      h1q.v = *(const float4*)&h_s[k][4];
      h2q.v = *(const float4*)&h_s[k][8];
      h3q.v = *(const float4*)&h_s[k][12];
      F4 wv4; wv4.v = *(const float4*)&WhhT4[(k << 10) + (u << 2)];
      #pragma unroll
      for (int j = 0; j < 4; ++j) {
        #pragma unroll
        for (int g = 0; g < 4; ++g) {
          ga[j][g]      = fmaf(h0q.f[j], wv4.f[g], ga[j][g]);
          ga[4 + j][g]  = fmaf(h1q.f[j], wv4.f[g], ga[4 + j][g]);
          ga[8 + j][g]  = fmaf(h2q.f[j], wv4.f[g], ga[8 + j][g]);
          ga[12 + j][g] = fmaf(h3q.f[j], wv4.f[g], ga[12 + j][g]);
        }
      }
    }
    __syncthreads();  // all reads of h_s done before overwrite
    float hn[16];
    #pragma unroll
    for (int s = 0; s < 16; ++s) {
      float gi = ga[s][0] + bg[0];
      float gf = ga[s][1] + bg[1];
      float gg = ga[s][2] + bg[2];
      float go = ga[s][3] + bg[3];
      float cn = sigm(gf) * c_r[s] + sigm(gi) * tanhf(gg);
      hn[s] = sigm(go) * tanhf(cn);
      c_r[s] = cn;
    }
    #pragma unroll
    for (int q = 0; q < 4; ++q) {
      F4 hv4;
      #pragma unroll
      for (int j = 0; j < 4; ++j) hv4.f[j] = hn[q * 4 + j];
      *(float4*)&h_s[u][q * 4] = hv4.v;
    }
    __syncthreads();
  }

  // ---- 20 sampled steps ----
  for (int l = 0; l < NSTEP; ++l) {
    uint32_t kl0, kl1;
    threefry2x32(0u, 42u, 0u, (uint32_t)l, kl0, kl1);

    const bool last = (l == NSTEP - 1);
    float la[4] = {0.0f, 0.0f, 0.0f, 0.0f};  // logits for samples 4w..+3, v=lane
    float ga[16][4];
    #pragma unroll
    for (int s = 0; s < 16; ++s)
      #pragma unroll
      for (int g = 0; g < 4; ++g) ga[s][g] = 0.0f;

    if (!last) {
      #pragma unroll 2
      for (int k = 0; k < HDIM; ++k) {
        F4 h0q, h1q, h2q, h3q, hl;
        h0q.v = *(const float4*)&h_s[k][0];
        h1q.v = *(const float4*)&h_s[k][4];
        h2q.v = *(const float4*)&h_s[k][8];
        h3q.v = *(const float4*)&h_s[k][12];
        hl.v  = *(const float4*)&h_s[k][w4];   // this wave's 4 logit samples
        F4 wv4; wv4.v = *(const float4*)&WhhT4[(k << 10) + (u << 2)];
        float wvv = WvT[(k << 6) | lane];
        #pragma unroll
        for (int s = 0; s < 4; ++s) la[s] = fmaf(hl.f[s], wvv, la[s]);
        #pragma unroll
        for (int j = 0; j < 4; ++j) {
          #pragma unroll
          for (int g = 0; g < 4; ++g) {
            ga[j][g]      = fmaf(h0q.f[j], wv4.f[g], ga[j][g]);
            ga[4 + j][g]  = fmaf(h1q.f[j], wv4.f[g], ga[4 + j][g]);
            ga[8 + j][g]  = fmaf(h2q.f[j], wv4.f[g], ga[8 + j][g]);
            ga[12 + j][g] = fmaf(h3q.f[j], wv4.f[g], ga[12 + j][g]);
          }
        }
      }
    } else {
      #pragma unroll 2
      for (int k = 0; k < HDIM; ++k) {
        F4 hl; hl.v = *(const float4*)&h_s[k][w4];
        float wvv = WvT[(k << 6) | lane];
        #pragma unroll
        for (int s = 0; s < 4; ++s) la[s] = fmaf(hl.f[s], wvv, la[s]);
      }
    }

    // ---- sampling: wave w handles samples 4w..+3; lane holds logit[b][lane] ----
    #pragma unroll
    for (int db = 0; db < 4; ++db) {
      float x = la[db] + bv;  // logits = h@W_v^T + b_v
      float m = x;
      #pragma unroll
      for (int o = 32; o > 0; o >>= 1) m = fmaxf(m, __shfl_xor(m, o));
      float e = expf(x - m);
      float s = e;
      #pragma unroll
      for (int o = 32; o > 0; o >>= 1) s += __shfl_xor(s, o);
      float lse = logf(s);
      float logp = x - m - lse;
      float p = expf(logp);
      float pe = p * logp;
      #pragma unroll
      for (int o = 32; o > 0; o >>= 1) pe += __shfl_xor(pe, o);
      uint32_t idx = ((uint32_t)(b0 + w4 + db) << 6) | (uint32_t)lane;
      uint32_t r0, r1;
      threefry2x32(kl0, kl1, 0u, idx, r0, r1);
      uint32_t bits = r0 ^ r1;
      float f01 = __uint_as_float((bits >> 9) | 0x3f800000u) - 1.0f;
      const float TINY = 1.17549435e-38f;
      float uu2 = fmaxf(TINY, f01 + TINY);
      float gn = -logf(-logf(uu2));
      float y = gn + x;
      float by = y; int bi = lane;
      #pragma unroll
      for (int o = 32; o > 0; o >>= 1) {
        float oy = __shfl_xor(by, o);
        int oi = __shfl_xor(bi, o);
        if (oy > by || (oy == by && oi < bi)) { by = oy; bi = oi; }
      }
      float lp = __shfl(logp, bi, 64);
      if (lane == 0) {
        int bb = w4 + db;
        ch_s[bb] = bi;
        slp_s[bb] += lp;
        plp_s[bb] += pe;
        ep_s[bb] *= expf(lp);
        out[(size_t)(b0 + bb) * NSTEP + l] = (float)bi;
      }
    }

    if (!last) {
      __syncthreads();  // everyone finished reading h_s; ch_s visible
      float hn[16];
      #pragma unroll
      for (int s = 0; s < 16; ++s) {
        F4 wi; wi.v = *(const float4*)&WihT4[(ch_s[s] << 10) + (u << 2)];
        float gi = ga[s][0] + wi.f[0] + bg[0];
        float gf = ga[s][1] + wi.f[1] + bg[1];
        float gg = ga[s][2] + wi.f[2] + bg[2];
        float go = ga[s][3] + wi.f[3] + bg[3];
        float cn = sigm(gf) * c_r[s] + sigm(gi) * tanhf(gg);
        hn[s] = sigm(go) * tanhf(cn);
        c_r[s] = cn;
      }
      #pragma unroll
      for (int q = 0; q < 4; ++q) {
        F4 hv4;
        #pragma unroll
        for (int j = 0; j < 4; ++j) hv4.f[j] = hn[q * 4 + j];
        *(float4*)&h_s[u][q * 4] = hv4.v;
      }
      __syncthreads();
    }
  }

  __syncthreads();
  if (tid < TB) {
    int bb = b0 + tid;
    out[(size_t)BATCH * NSTEP + bb]             = slp_s[tid];
    out[(size_t)BATCH * NSTEP + BATCH + bb]     = plp_s[tid];
    out[(size_t)BATCH * NSTEP + 2 * BATCH + bb] = ep_s[tid];
  }
}

extern "C" void kernel_launch(void* const* d_in, const int* in_sizes, int n_in,
                              void* d_out, int out_size, void* d_ws, size_t ws_size,
                              hipStream_t stream) {
  // setup_inputs order:
  // 0 attrVector [8192,128], 1 W_a [256,128], 2 b_a [256], 3 W_ih [1024,64],
  // 4 W_hh [1024,256], 5 b_ih [1024], 6 b_hh [1024], 7 W_v [64,256], 8 b_v [64]
  const float* attr = (const float*)d_in[0];
  const float* W_a  = (const float*)d_in[1];
  const float* b_a  = (const float*)d_in[2];
  const float* W_ih = (const float*)d_in[3];
  const float* W_hh = (const float*)d_in[4];
  const float* b_ih = (const float*)d_in[5];
  const float* b_hh = (const float*)d_in[6];
  const float* W_v  = (const float*)d_in[7];
  const float* b_v  = (const float*)d_in[8];
  float* ws = (float*)d_ws;

  prep_kernel<<<256, 256, 0, stream>>>(W_hh, W_v, W_a, W_ih, ws);
  sender_main<<<BATCH / TB, 256, 0, stream>>>(
      attr, b_a, b_ih, b_hh, b_v,
      ws, ws + 262144, ws + 278528, ws + 311296,
      (float*)d_out);
}

// Round 6
// 1441.308 us; speedup vs baseline: 1.8317x; 1.0583x over previous
//
#include <hip/hip_runtime.h>
#include <stdint.h>

#define BATCH 8192
#define ADIM 128
#define HDIM 256
#define VDIM 64
#define NSTEP 20
#define TB 16
#define HSP 17   // h_s stride (floats): ODD -> lane-distributed b32 reads are conflict-free
#define ASP 20   // attr_s stride: 16B-aligned rows for b128 staging reads

typedef union { float4 v; float f[4]; } F4;

// ---------------- Threefry-2x32 (exactly JAX's lowering) ----------------
__device__ __forceinline__ uint32_t rotl32(uint32_t x, uint32_t d) {
  return (x << d) | (x >> (32u - d));
}
__device__ __forceinline__ void tf4(uint32_t& x0, uint32_t& x1, int r0, int r1, int r2, int r3) {
  x0 += x1; x1 = rotl32(x1, r0); x1 ^= x0;
  x0 += x1; x1 = rotl32(x1, r1); x1 ^= x0;
  x0 += x1; x1 = rotl32(x1, r2); x1 ^= x0;
  x0 += x1; x1 = rotl32(x1, r3); x1 ^= x0;
}
__device__ __forceinline__ void threefry2x32(uint32_t k0, uint32_t k1, uint32_t x0, uint32_t x1,
                                             uint32_t& o0, uint32_t& o1) {
  uint32_t k2 = k0 ^ k1 ^ 0x1BD11BDAu;
  x0 += k0; x1 += k1;
  tf4(x0, x1, 13, 15, 26, 6);  x0 += k1; x1 += k2 + 1u;
  tf4(x0, x1, 17, 29, 16, 24); x0 += k2; x1 += k0 + 2u;
  tf4(x0, x1, 13, 15, 26, 6);  x0 += k0; x1 += k1 + 3u;
  tf4(x0, x1, 17, 29, 16, 24); x0 += k1; x1 += k2 + 4u;
  tf4(x0, x1, 13, 15, 26, 6);  x0 += k2; x1 += k0 + 5u;
  o0 = x0; o1 = x1;
}

__device__ __forceinline__ float sigm(float x) { return 1.0f / (1.0f + expf(-x)); }

// wave-uniform broadcast of lane t's value -> SGPR (feeds v_fma scalar slot)
__device__ __forceinline__ float bcast(float x, int t) {
  return __int_as_float(__builtin_amdgcn_readlane(__float_as_int(x), t));
}

// ---------------- prep: repack weights, gate-interleaved per unit ----------------
// ws layout (floats): WhhT4[256][256][4] @0      (k, unit, gate)  1 MB
//                     WvT  [256][64]     @262144 (k, v)
//                     WaT  [128][256]    @278528 (k, unit)
//                     WihT4[64][256][4]  @311296 (v, unit, gate)
__global__ void prep_kernel(const float* __restrict__ Whh, const float* __restrict__ Wv,
                            const float* __restrict__ Wa, const float* __restrict__ Wih,
                            float* __restrict__ ws) {
  int n = blockIdx.x * blockDim.x + threadIdx.x;
  int stride = gridDim.x * blockDim.x;
  float* WhhT4 = ws;
  float* WvT   = ws + 262144;
  float* WaT   = ws + 278528;
  float* WihT4 = ws + 311296;
  for (int i = n; i < 256 * 1024; i += stride) {
    int k = i >> 10, rem = i & 1023, u = rem >> 2, g = rem & 3;
    WhhT4[i] = Whh[((g << 8) + u) * 256 + k];
  }
  for (int i = n; i < 256 * 64; i += stride) { int k = i >> 6, v = i & 63; WvT[i] = Wv[v * 256 + k]; }
  for (int i = n; i < 128 * 256; i += stride) { int k = i >> 8, u = i & 255; WaT[i] = Wa[u * 128 + k]; }
  for (int i = n; i < 64 * 1024; i += stride) {
    int v = i >> 10, rem = i & 1023, u = rem >> 2, g = rem & 3;
    WihT4[i] = Wih[((g << 8) + u) * 64 + v];
  }
}

// ---------------- main persistent kernel ----------------
// 512 blocks x 256 threads; block owns TB=16 samples for all 21 steps.
// Lane = unit (u = 64w+lane); thread computes 4 gates x 16 samples for its unit.
// h broadcast via chunked lane-distribution + v_readlane (SGPR operand of
// v_fma): kills the R5 LDS bottleneck (5 broadcast b128/k = 5KB/wave/k of
// LDS return traffic -> 256 B/wave/k).
// Per-wave sample rotation: thread-local slot s holds PHYSICAL sample
// (s+4w)&15, so the wave's logit samples are always slots 0..3 (compile-time
// register indices; dynamic indices only touch LDS). Identical FMA values
// and k-order -> bit-exact vs R5/reference.
__global__ __launch_bounds__(256, 2) void sender_main(
    const float* __restrict__ attr, const float* __restrict__ b_a,
    const float* __restrict__ b_ih, const float* __restrict__ b_hh,
    const float* __restrict__ b_v,
    const float* __restrict__ WhhT4, const float* __restrict__ WvT,
    const float* __restrict__ WaT, const float* __restrict__ WihT4,
    float* __restrict__ out) {
  __shared__ float h_s[HDIM][HSP];                    // h_s[k][phys sample]
  __shared__ __align__(16) float attr_s[ADIM][ASP];   // attr_s[k][sample]
  __shared__ float slp_s[TB], plp_s[TB], ep_s[TB];
  __shared__ int ch_s[TB];

  const int tid = threadIdx.x;
  const int w = tid >> 6;         // wave id
  const int lane = tid & 63;
  const int u = (w << 6) + lane;  // unit owned by this thread
  const int w4 = w << 2;          // first (physical) sample this wave samples
  const int b0 = blockIdx.x * TB;

  if (tid < TB) { slp_s[tid] = 0.0f; plp_s[tid] = 0.0f; ep_s[tid] = 1.0f; }

  // ---- stage attr tile, transposed to k-major ----
  {
    int r = tid >> 5;            // 0..7
    int cm = (tid & 31) << 2;    // 0,4,...,124
    #pragma unroll
    for (int pass = 0; pass < 2; ++pass) {
      int row = r + (pass << 3);
      F4 vv; vv.v = *(const float4*)&attr[(size_t)(b0 + row) * ADIM + cm];
      attr_s[cm + 0][row] = vv.f[0];
      attr_s[cm + 1][row] = vv.f[1];
      attr_s[cm + 2][row] = vv.f[2];
      attr_s[cm + 3][row] = vv.f[3];
    }
  }
  __syncthreads();

  // ---- h0 = attr @ W_a^T + b_a : acc[phys sample] for this thread's unit ----
  {
    float acc[16];
    #pragma unroll
    for (int s = 0; s < 16; ++s) acc[s] = 0.0f;
    #pragma unroll 2
    for (int k = 0; k < ADIM; ++k) {
      F4 a0, a1, a2, a3;
      a0.v = *(const float4*)&attr_s[k][0];
      a1.v = *(const float4*)&attr_s[k][4];
      a2.v = *(const float4*)&attr_s[k][8];
      a3.v = *(const float4*)&attr_s[k][12];
      float wa = WaT[(k << 8) + u];
      #pragma unroll
      for (int j = 0; j < 4; ++j) {
        acc[j]      = fmaf(a0.f[j], wa, acc[j]);
        acc[4 + j]  = fmaf(a1.f[j], wa, acc[4 + j]);
        acc[8 + j]  = fmaf(a2.f[j], wa, acc[8 + j]);
        acc[12 + j] = fmaf(a3.f[j], wa, acc[12 + j]);
      }
    }
    float ba = b_a[u];
    #pragma unroll
    for (int s = 0; s < 16; ++s) h_s[u][s] = acc[s] + ba;
  }
  __syncthreads();

  // persistent per-thread state: cell state, slot s = phys sample (s+w4)&15
  float c_r[16];
  #pragma unroll
  for (int s = 0; s < 16; ++s) c_r[s] = 0.0f;

  float bg[4];  // b_ih + b_hh per gate for this unit
  #pragma unroll
  for (int g = 0; g < 4; ++g) bg[g] = b_ih[(g << 8) + u] + b_hh[(g << 8) + u];
  const float bv = b_v[lane];

  // ---- initial LSTM step, x = 0 ----
  {
    float ga[16][4];  // [slot][gate]
    #pragma unroll
    for (int s = 0; s < 16; ++s)
      #pragma unroll
      for (int g = 0; g < 4; ++g) ga[s][g] = 0.0f;
    #pragma unroll 1
    for (int kc = 0; kc < 16; ++kc) {
      const int k0 = kc << 4;
      const int kk = k0 + (lane & 15);
      float hch[16];
      #pragma unroll
      for (int s = 0; s < 16; ++s) hch[s] = h_s[kk][(s + w4) & 15];
      #pragma unroll
      for (int t = 0; t < 16; ++t) {
        const int k = k0 + t;
        F4 wv4; wv4.v = *(const float4*)&WhhT4[(k << 10) + (u << 2)];
        #pragma unroll
        for (int s = 0; s < 16; ++s) {
          float hb = bcast(hch[s], t);
          ga[s][0] = fmaf(hb, wv4.f[0], ga[s][0]);
          ga[s][1] = fmaf(hb, wv4.f[1], ga[s][1]);
          ga[s][2] = fmaf(hb, wv4.f[2], ga[s][2]);
          ga[s][3] = fmaf(hb, wv4.f[3], ga[s][3]);
        }
      }
    }
    __syncthreads();  // all reads of h_s done before overwrite
    float hn[16];
    #pragma unroll
    for (int s = 0; s < 16; ++s) {
      float gi = ga[s][0] + bg[0];
      float gf = ga[s][1] + bg[1];
      float gg = ga[s][2] + bg[2];
      float go = ga[s][3] + bg[3];
      float cn = sigm(gf) * c_r[s] + sigm(gi) * tanhf(gg);
      hn[s] = sigm(go) * tanhf(cn);
      c_r[s] = cn;
    }
    #pragma unroll
    for (int s = 0; s < 16; ++s) h_s[u][(s + w4) & 15] = hn[s];
    __syncthreads();
  }

  // ---- 20 sampled steps ----
  #pragma unroll 1
  for (int l = 0; l < NSTEP; ++l) {
    uint32_t kl0, kl1;
    threefry2x32(0u, 42u, 0u, (uint32_t)l, kl0, kl1);

    const bool last = (l == NSTEP - 1);
    float la[4] = {0.0f, 0.0f, 0.0f, 0.0f};  // logits for phys samples w4..w4+3, v=lane
    float ga[16][4];  // [slot][gate]
    #pragma unroll
    for (int s = 0; s < 16; ++s)
      #pragma unroll
      for (int g = 0; g < 4; ++g) ga[s][g] = 0.0f;

    if (!last) {
      #pragma unroll 1
      for (int kc = 0; kc < 16; ++kc) {
        const int k0 = kc << 4;
        const int kk = k0 + (lane & 15);
        float hch[16];
        #pragma unroll
        for (int s = 0; s < 16; ++s) hch[s] = h_s[kk][(s + w4) & 15];
        #pragma unroll
        for (int t = 0; t < 16; ++t) {
          const int k = k0 + t;
          F4 wv4; wv4.v = *(const float4*)&WhhT4[(k << 10) + (u << 2)];
          float wvv = WvT[(k << 6) | lane];
          #pragma unroll
          for (int s = 0; s < 16; ++s) {
            float hb = bcast(hch[s], t);
            if (s < 4) la[s] = fmaf(hb, wvv, la[s]);  // slots 0..3 = phys w4..w4+3
            ga[s][0] = fmaf(hb, wv4.f[0], ga[s][0]);
            ga[s][1] = fmaf(hb, wv4.f[1], ga[s][1]);
            ga[s][2] = fmaf(hb, wv4.f[2], ga[s][2]);
            ga[s][3] = fmaf(hb, wv4.f[3], ga[s][3]);
          }
        }
      }
    } else {
      // logits only
      #pragma unroll 1
      for (int kc = 0; kc < 16; ++kc) {
        const int k0 = kc << 4;
        const int kk = k0 + (lane & 15);
        float hch[4];
        #pragma unroll
        for (int s = 0; s < 4; ++s) hch[s] = h_s[kk][(s + w4) & 15];
        #pragma unroll
        for (int t = 0; t < 16; ++t) {
          const int k = k0 + t;
          float wvv = WvT[(k << 6) | lane];
          #pragma unroll
          for (int s = 0; s < 4; ++s) la[s] = fmaf(bcast(hch[s], t), wvv, la[s]);
        }
      }
    }

    // ---- sampling: wave w handles phys samples w4..w4+3; lane holds logit[b][lane] ----
    #pragma unroll
    for (int db = 0; db < 4; ++db) {
      float x = la[db] + bv;  // logits = h@W_v^T + b_v
      float m = x;
      #pragma unroll
      for (int o = 32; o > 0; o >>= 1) m = fmaxf(m, __shfl_xor(m, o));
      float e = expf(x - m);
      float s = e;
      #pragma unroll
      for (int o = 32; o > 0; o >>= 1) s += __shfl_xor(s, o);
      float lse = logf(s);
      float logp = x - m - lse;
      float p = expf(logp);
      float pe = p * logp;
      #pragma unroll
      for (int o = 32; o > 0; o >>= 1) pe += __shfl_xor(pe, o);
      uint32_t idx = ((uint32_t)(b0 + w4 + db) << 6) | (uint32_t)lane;
      uint32_t r0, r1;
      threefry2x32(kl0, kl1, 0u, idx, r0, r1);
      uint32_t bits = r0 ^ r1;
      float f01 = __uint_as_float((bits >> 9) | 0x3f800000u) - 1.0f;
      const float TINY = 1.17549435e-38f;
      float uu2 = fmaxf(TINY, f01 + TINY);
      float gn = -logf(-logf(uu2));
      float y = gn + x;
      float by = y; int bi = lane;
      #pragma unroll
      for (int o = 32; o > 0; o >>= 1) {
        float oy = __shfl_xor(by, o);
        int oi = __shfl_xor(bi, o);
        if (oy > by || (oy == by && oi < bi)) { by = oy; bi = oi; }
      }
      float lp = __shfl(logp, bi, 64);
      if (lane == 0) {
        int bb = w4 + db;
        ch_s[bb] = bi;
        slp_s[bb] += lp;
        plp_s[bb] += pe;
        ep_s[bb] *= expf(lp);
        out[(size_t)(b0 + bb) * NSTEP + l] = (float)bi;
      }
    }

    if (!last) {
      __syncthreads();  // everyone finished reading h_s; ch_s visible
      float hn[16];
      #pragma unroll
      for (int s = 0; s < 16; ++s) {
        const int sp = (s + w4) & 15;  // physical sample for this slot
        F4 wi; wi.v = *(const float4*)&WihT4[(ch_s[sp] << 10) + (u << 2)];
        float gi = ga[s][0] + wi.f[0] + bg[0];
        float gf = ga[s][1] + wi.f[1] + bg[1];
        float gg = ga[s][2] + wi.f[2] + bg[2];
        float go = ga[s][3] + wi.f[3] + bg[3];
        float cn = sigm(gf) * c_r[s] + sigm(gi) * tanhf(gg);
        hn[s] = sigm(go) * tanhf(cn);
        c_r[s] = cn;
      }
      #pragma unroll
      for (int s = 0; s < 16; ++s) h_s[u][(s + w4) & 15] = hn[s];
      __syncthreads();
    }
  }

  __syncthreads();
  if (tid < TB) {
    int bb = b0 + tid;
    out[(size_t)BATCH * NSTEP + bb]             = slp_s[tid];
    out[(size_t)BATCH * NSTEP + BATCH + bb]     = plp_s[tid];
    out[(size_t)BATCH * NSTEP + 2 * BATCH + bb] = ep_s[tid];
  }
}

extern "C" void kernel_launch(void* const* d_in, const int* in_sizes, int n_in,
                              void* d_out, int out_size, void* d_ws, size_t ws_size,
                              hipStream_t stream) {
  // setup_inputs order:
  // 0 attrVector [8192,128], 1 W_a [256,128], 2 b_a [256], 3 W_ih [1024,64],
  // 4 W_hh [1024,256], 5 b_ih [1024], 6 b_hh [1024], 7 W_v [64,256], 8 b_v [64]
  const float* attr = (const float*)d_in[0];
  const float* W_a  = (const float*)d_in[1];
  const float* b_a  = (const float*)d_in[2];
  const float* W_ih = (const float*)d_in[3];
  const float* W_hh = (const float*)d_in[4];
  const float* b_ih = (const float*)d_in[5];
  const float* b_hh = (const float*)d_in[6];
  const float* W_v  = (const float*)d_in[7];
  const float* b_v  = (const float*)d_in[8];
  float* ws = (float*)d_ws;

  prep_kernel<<<256, 256, 0, stream>>>(W_hh, W_v, W_a, W_ih, ws);
  sender_main<<<BATCH / TB, 256, 0, stream>>>(
      attr, b_a, b_ih, b_hh, b_v,
      ws, ws + 262144, ws + 278528, ws + 311296,
      (float*)d_out);
}